// Round 7
// baseline (162.923 us; speedup 1.0000x reference)
//
#include <hip/hip_runtime.h>
#include <hip/hip_bf16.h>
#include <stdint.h>

// LocalSlidingWindowAttention: B=2, T=2048, D=1024, H=16, hd=64, keys j in [i, i+64].
// f32 in/out. Build:
//   convert_all (r7) -> gemm1_qkv_8ph (r7 NEW: faithful m201 8-phase port — BK=64,
//   2buf x 2 kh-halves, 4 phases/K-tile {4-8 ds_read | 1 half-tile stage | bar |
//   lgkm0 | 16 MFMA | bar}, staggered half-tile staging, counted vmcnt(4)/K-tile)
//   -> attn_mfma (r3, proven) -> gemm2_out (r8, proven).
// gemm1 history: 128^2 m97 43.7us -> 8ph drain0 46.0 (m218 confirmed) -> 4-deep
//   counted BK=32 42.3 (BANK_CONFLICT 4cyc/b128) -> r6 1-bar/tile+swz ~36 (est;
//   total 152.5). r7 = m201 interleave (proven 1563 TF @4k on this structure).
// Stagger ledger (2 loads per half-tile stage): end of tile j outstanding =
//   {A0,B0(j+1) [from j-1 ph2,3], A1,B1(j+1) [j ph0,1], A0,B0(j+2) [j ph2,3]} = 12
//   -> vmcnt(4) retires exactly tile j+1. Tail: vmcnt(0) at nk-2, none at nk-1.
// Stage-write safety: each target region is dead (readers lgkm0'd + barrier'd)
//   >= 1 phase before the stage issue; 2 barriers/phase make this cross-wave-safe.

typedef short bf16x8 __attribute__((ext_vector_type(8)));
typedef float f32x4 __attribute__((ext_vector_type(4)));

typedef const __attribute__((address_space(1))) void* gptr_t;
typedef __attribute__((address_space(3))) void* lptr_t;

#define BAR()        asm volatile("s_barrier" ::: "memory")
#define WAIT_LGKM0() asm volatile("s_waitcnt lgkmcnt(0)" ::: "memory")

__device__ __forceinline__ float bf2f(short u) {
    union { float f; uint32_t i; } x;
    x.i = ((uint32_t)(uint16_t)u) << 16;
    return x.f;
}
__device__ __forceinline__ short f2bf(float f) {
    __hip_bfloat16 h = __float2bfloat16(f);  // RNE
    return *reinterpret_cast<short*>(&h);
}

// Convert x, w_qkv, w_out to bf16. 8 elems/thread.
__global__ __launch_bounds__(256)
void convert_all(const float* __restrict__ x, const float* __restrict__ wq,
                 const float* __restrict__ wo,
                 short* __restrict__ xb, short* __restrict__ wqb, short* __restrict__ wob) {
    int i = blockIdx.x * 256 + threadIdx.x;
    const float* src; short* dst; int o;
    if      (i <  524288) { src = x;  dst = xb;  o = i; }
    else if (i <  917504) { src = wq; dst = wqb; o = i - 524288; }
    else                  { src = wo; dst = wob; o = i - 917504; }
    const int e = o * 8;
    float4 a = *(const float4*)(src + e);
    float4 b = *(const float4*)(src + e + 4);
    short t[8];
    t[0] = f2bf(a.x); t[1] = f2bf(a.y); t[2] = f2bf(a.z); t[3] = f2bf(a.w);
    t[4] = f2bf(b.x); t[5] = f2bf(b.y); t[6] = f2bf(b.z); t[7] = f2bf(b.w);
    *(uint4*)(dst + e) = *(const uint4*)t;
}

// GEMM1: C[m,n] = sum_k A[m,k]*Bt[n,k] + bias[n], bf16 out. 256x256, BK=64.
// 512 threads = 8 waves (2M x 4N), per-wave 128x64, acc[8][4].
// LDS: As/Bs[buf][kh][256*32] = 128 KiB. Phase (kh,H): read A rows
// wm*128+H*64+mi*16+l16 (4 reads) + B (4 reads, only H==0); stage 1 half-tile;
// BAR; lgkm0; 16 MFMA (setprio-wrapped); [VM endwait]; BAR.
// Swizzle (both-sides, r6-verified): LDS[.][kh][row][slot] holds global chunk
// slot^((row>>1)&3) of the kh 32-col block; read slot = qd^((l16>>1)&3) (const).
__global__ __launch_bounds__(512, 1)
void gemm1_qkv_8ph(const short* __restrict__ A, const short* __restrict__ Bt,
                   const float* __restrict__ bias, short* __restrict__ C,
                   int M, int N, int K) {
    __shared__ short As[2][2][256 * 32];   // [buf][kh], 64 KiB
    __shared__ short Bs[2][2][256 * 32];   // 64 KiB

    const int tid  = threadIdx.x;
    const int lane = tid & 63;
    const int w    = tid >> 6;        // 0..7
    const int qd   = lane >> 4;       // 0..3
    const int l16  = lane & 15;
    const int wm   = w >> 2;          // 0..1  (128 rows each)
    const int wn   = w & 3;           // 0..3  (64 cols each)
    const int sx8  = (qd ^ ((l16 >> 1) & 3)) * 8;   // swizzled read slot (shorts)

    // XCD-chunked bijective swizzle (nwg=192, 192%8==0).
    const int nTn   = N >> 8;                     // 12
    const int chunk = gridDim.x >> 3;             // 24
    const int wg    = (blockIdx.x & 7) * chunk + (blockIdx.x >> 3);
    const int mt    = wg / nTn;
    const int nt    = wg - mt * nTn;
    const int mBase = mt << 8;
    const int nBase = nt << 8;

    // Staging sources: half-tile = 256 rows x 32 cols = 16 KB = 1024 granules of
    // 16B; granule g = rr*512 + tid: row = g>>2, stored slot = g&3, source chunk
    // pre-XOR'd (g&3)^((g>>3)&3)  [= slot ^ ((row>>1)&3), the read involution].
    const short* gA[2];
    const short* gB[2];
#pragma unroll
    for (int rr = 0; rr < 2; ++rr) {
        const int g    = rr * 512 + tid;
        const int row  = g >> 2;
        const int slot = (g & 3) ^ ((g >> 3) & 3);
        gA[rr] = A  + (size_t)(mBase + row) * K + slot * 8;
        gB[rr] = Bt + (size_t)(nBase + row) * K + slot * 8;
    }

    f32x4 acc[8][4] = {};
    bf16x8 af_[4], bfr_[2][4];
    const int nk = K >> 6;                        // 16 (requires nk >= 3)

#define STAGE_A(T, KH) { _Pragma("unroll")                                        \
    for (int rr = 0; rr < 2; ++rr)                                                \
        __builtin_amdgcn_global_load_lds(                                         \
            (gptr_t)(gA[rr] + (size_t)(T) * 64 + (KH) * 32),                      \
            (lptr_t)(&As[(T) & 1][KH][0] + (rr * 512 + w * 64) * 8), 16, 0, 0); }
#define STAGE_B(T, KH) { _Pragma("unroll")                                        \
    for (int rr = 0; rr < 2; ++rr)                                                \
        __builtin_amdgcn_global_load_lds(                                         \
            (gptr_t)(gB[rr] + (size_t)(T) * 64 + (KH) * 32),                      \
            (lptr_t)(&Bs[(T) & 1][KH][0] + (rr * 512 + w * 64) * 8), 16, 0, 0); }
#define VM4  asm volatile("s_waitcnt vmcnt(4)" ::: "memory")
#define VM0  asm volatile("s_waitcnt vmcnt(0)" ::: "memory")
#define NOPW (void)0

    // Prologue: t0 all 4 halves, t1 A-kh0,B-kh0 (12 loads); retire t0 -> vmcnt(4).
    STAGE_A(0, 0) STAGE_B(0, 0) STAGE_A(0, 1) STAGE_B(0, 1)
    STAGE_A(1, 0) STAGE_B(1, 0)
    VM4;
    BAR();

#define PHASE(KT, KH, H, STAGE_STMT, ENDW)                                        \
    {                                                                             \
        const short* Ak_ = &As[(KT) & 1][KH][0];                                  \
        _Pragma("unroll")                                                         \
        for (int mi = 0; mi < 4; ++mi)                                            \
            af_[mi] = *(const bf16x8*)(Ak_ + (wm * 128 + (H) * 64 + mi * 16 + l16) * 32 + sx8); \
        if ((H) == 0) {                                                           \
            const short* Bk_ = &Bs[(KT) & 1][KH][0];                              \
            _Pragma("unroll")                                                     \
            for (int ni = 0; ni < 4; ++ni)                                        \
                bfr_[KH][ni] = *(const bf16x8*)(Bk_ + (wn * 64 + ni * 16 + l16) * 32 + sx8); \
        }                                                                         \
        STAGE_STMT;                                                               \
        BAR();                                                                    \
        WAIT_LGKM0();                                                             \
        __builtin_amdgcn_sched_barrier(0);                                        \
        __builtin_amdgcn_s_setprio(1);                                            \
        _Pragma("unroll")                                                         \
        for (int mi = 0; mi < 4; ++mi)                                            \
            _Pragma("unroll")                                                     \
            for (int ni = 0; ni < 4; ++ni)                                        \
                acc[(H) * 4 + mi][ni] = __builtin_amdgcn_mfma_f32_16x16x32_bf16(  \
                    af_[mi], bfr_[KH][ni], acc[(H) * 4 + mi][ni], 0, 0, 0);       \
        __builtin_amdgcn_s_setprio(0);                                            \
        ENDW;                                                                     \
        BAR();                                                                    \
    }

    // Main loop: tiles 0..nk-3. Stagger: ph0->A1(j+1), ph1->B1(j+1),
    // ph2->A0(j+2), ph3->B0(j+2); end-of-tile vmcnt(4) retires tile j+1.
    for (int kt = 0; kt <= nk - 3; ++kt) {
        PHASE(kt, 0, 0, STAGE_A(kt + 1, 1), NOPW)
        PHASE(kt, 0, 1, STAGE_B(kt + 1, 1), NOPW)
        PHASE(kt, 1, 0, STAGE_A(kt + 2, 0), NOPW)
        PHASE(kt, 1, 1, STAGE_B(kt + 2, 0), VM4)
    }
    // Tile nk-2: finish staging tile nk-1; drain at end.
    PHASE(nk - 2, 0, 0, STAGE_A(nk - 1, 1), NOPW)
    PHASE(nk - 2, 0, 1, STAGE_B(nk - 1, 1), NOPW)
    PHASE(nk - 2, 1, 0, NOPW, NOPW)
    PHASE(nk - 2, 1, 1, NOPW, VM0)
    // Tile nk-1: compute only.
    PHASE(nk - 1, 0, 0, NOPW, NOPW)
    PHASE(nk - 1, 0, 1, NOPW, NOPW)
    PHASE(nk - 1, 1, 0, NOPW, NOPW)
    PHASE(nk - 1, 1, 1, NOPW, NOPW)
#undef PHASE
#undef STAGE_A
#undef STAGE_B
#undef VM4
#undef VM0
#undef NOPW

    // Epilogue: n = ..+l16 (lane-consecutive), m = ..+qd*4+rr (proven mapping).
#pragma unroll
    for (int nf = 0; nf < 4; ++nf) {
        const int n = nBase + wn * 64 + nf * 16 + l16;
        const float bv = bias[n];
#pragma unroll
        for (int mf = 0; mf < 8; ++mf)
#pragma unroll
            for (int rr = 0; rr < 4; ++rr) {
                const int m = mBase + wm * 128 + mf * 16 + qd * 4 + rr;
                C[(size_t)m * N + n] = f2bf(acc[mf][nf][rr] + bv);
            }
    }
}

// GEMM2 (r8 proven component): out = attn @ w_out^T + b_out, f32 out/bias.
// 64x128 tile, BK=32. Grid (8,64) = 512 blocks = 2/CU (12 KB LDS) -> drain overlap.
__global__ __launch_bounds__(256)
void gemm2_out(const short* __restrict__ A, const short* __restrict__ Bt,
               const float* __restrict__ bias, float* __restrict__ C,
               int M, int N, int K) {
    __shared__ short As[64 * 32];    // 4 KB
    __shared__ short Bs[128 * 32];   // 8 KB

    const int tid  = threadIdx.x;
    const int lane = tid & 63;
    const int w    = tid >> 6;
    const int qd   = lane >> 4;
    const int l16  = lane & 15;
    const int wm   = w >> 1;          // 32 rows each
    const int wn   = w & 1;           // 64 cols each
    const int mBase = blockIdx.y * 64;
    const int nBase = blockIdx.x * 128;

    f32x4 acc[2][4] = {};

    const int nK = K >> 5;
    for (int kt = 0; kt < nK; ++kt) {
        const int kb = kt << 5;
        {
            const int e   = tid * 8;            // A: 64x32, one chunk-round
            const int row = e >> 5;
            const int col = e & 31;
            const short* ga = A + (size_t)(mBase + row) * K + kb + col;
            lptr_t la = (lptr_t)(As + w * 512);
            __builtin_amdgcn_global_load_lds((gptr_t)ga, la, 16, 0, 0);
        }
#pragma unroll
        for (int i = 0; i < 2; ++i) {           // B: 128x32
            const int e   = i * 2048 + tid * 8;
            const int row = e >> 5;
            const int col = e & 31;
            const short* gb = Bt + (size_t)(nBase + row) * K + kb + col;
            lptr_t lb = (lptr_t)(Bs + i * 2048 + w * 512);
            __builtin_amdgcn_global_load_lds((gptr_t)gb, lb, 16, 0, 0);
        }
        __syncthreads();

        bf16x8 af[2], bfr[4];
#pragma unroll
        for (int mi = 0; mi < 2; ++mi)
            af[mi] = *(const bf16x8*)(As + (wm * 32 + mi * 16 + l16) * 32 + qd * 8);
#pragma unroll
        for (int ni = 0; ni < 4; ++ni)
            bfr[ni] = *(const bf16x8*)(Bs + (wn * 64 + ni * 16 + l16) * 32 + qd * 8);
#pragma unroll
        for (int mi = 0; mi < 2; ++mi)
#pragma unroll
            for (int ni = 0; ni < 4; ++ni)
                acc[mi][ni] = __builtin_amdgcn_mfma_f32_16x16x32_bf16(
                    af[mi], bfr[ni], acc[mi][ni], 0, 0, 0);
        __syncthreads();
    }

#pragma unroll
    for (int ni = 0; ni < 4; ++ni) {
        const int n = nBase + wn * 64 + ni * 16 + l16;
        const float bv = bias[n];
#pragma unroll
        for (int mi = 0; mi < 2; ++mi)
#pragma unroll
            for (int rr = 0; rr < 4; ++rr) {
                const int m = mBase + wm * 32 + mi * 16 + qd * 4 + rr;
                C[(size_t)m * N + n] = acc[mi][ni][rr] + bv;
            }
    }
}

// MFMA attention (r3, proven). Block = 64 queries x head x batch; 4 waves.
__global__ __launch_bounds__(256)
void attn_mfma(const short* __restrict__ qkv, short* __restrict__ attn_out, int B, int T) {
    __shared__ short k_s[128 * 72];
    __shared__ short v_s[144 * 66];
    __shared__ short p_s[64 * 104];

    const int tid  = threadIdx.x;
    const int lane = tid & 63;
    const int w    = tid >> 6;
    const int qd   = lane >> 4;
    const int l16  = lane & 15;
    const int qs   = blockIdx.x * 64;
    const int h    = blockIdx.y;
    const int b    = blockIdx.z;
    const size_t rs   = 3072;
    const size_t base = (size_t)b * T * rs;
    const int qoff = h * 64, koff = 1024 + h * 64, voff = 2048 + h * 64;

#pragma unroll
    for (int i = 0; i < 5; ++i) {
        const int c   = tid + i * 256;
        const int row = c >> 3;
        if (row >= 144) break;
        const int ch = (c & 7) * 8;
        int gr = qs + row; if (gr > T - 1) gr = T - 1;
        uint4 uv = *(const uint4*)(qkv + base + (size_t)gr * rs + voff + ch);
        if (row < 128) {
            uint4 uk = *(const uint4*)(qkv + base + (size_t)gr * rs + koff + ch);
            *(uint4*)&k_s[row * 72 + ch] = uk;
        }
        const uint32_t* vp = (const uint32_t*)&uv;
        uint32_t* vd = (uint32_t*)&v_s[row * 66 + ch];
        vd[0] = vp[0]; vd[1] = vp[1]; vd[2] = vp[2]; vd[3] = vp[3];
    }
    __syncthreads();

    bf16x8 aq0, aq1;
    {
        const short* g = qkv + base + (size_t)(qs + 16 * w + l16) * rs + qoff + qd * 8;
        aq0 = *(const bf16x8*)(g);
        aq1 = *(const bf16x8*)(g + 32);
    }

    f32x4 sacc[5] = {};
#pragma unroll
    for (int u = 0; u < 5; ++u) {
        const int krow = 16 * (w + u) + l16;
        bf16x8 bk0 = *(const bf16x8*)&k_s[krow * 72 + qd * 8];
        bf16x8 bk1 = *(const bf16x8*)&k_s[krow * 72 + 32 + qd * 8];
        sacc[u] = __builtin_amdgcn_mfma_f32_16x16x32_bf16(aq0, bk0, sacc[u], 0, 0, 0);
        sacc[u] = __builtin_amdgcn_mfma_f32_16x16x32_bf16(aq1, bk1, sacc[u], 0, 0, 0);
    }

    const float scale = 0.125f;
    float pw[5][4];
    float inv[4];
#pragma unroll
    for (int r = 0; r < 4; ++r) {
        const int m = 4 * qd + r;
        float mx = -3.4e38f;
#pragma unroll
        for (int u = 0; u < 5; ++u) {
            const int rel = 16 * u + l16 - m;
            const int j   = qs + 16 * (w + u) + l16;
            const bool ok = (rel >= 0) & (rel <= 64) & (j < T);
            const float v = ok ? sacc[u][r] * scale : -3.4e38f;
            pw[u][r] = v;
            mx = fmaxf(mx, v);
        }
#pragma unroll
        for (int msk = 1; msk <= 8; msk <<= 1) mx = fmaxf(mx, __shfl_xor(mx, msk));
        float sum = 0.f;
#pragma unroll
        for (int u = 0; u < 5; ++u) {
            float e = (pw[u][r] <= -3.0e38f) ? 0.f : __expf(pw[u][r] - mx);
            pw[u][r] = e;
            sum += e;
        }
#pragma unroll
        for (int msk = 1; msk <= 8; msk <<= 1) sum += __shfl_xor(sum, msk);
        inv[r] = 1.0f / sum;
    }

#pragma unroll
    for (int u = 0; u < 5; ++u)
#pragma unroll
        for (int r = 0; r < 4; ++r)
            p_s[(16 * w + 4 * qd + r) * 104 + 16 * u + l16] = f2bf(pw[u][r] * inv[r]);
#pragma unroll
    for (int r = 0; r < 4; ++r)
        p_s[(16 * w + 4 * qd + r) * 104 + 80 + l16] = 0;
    // wave-private rows; same-wave RAW -> lgkmcnt wait, no barrier needed

    f32x4 oacc[4] = {};
#pragma unroll
    for (int ks = 0; ks < 3; ++ks) {
        bf16x8 ap = *(const bf16x8*)&p_s[(16 * w + l16) * 104 + ks * 32 + qd * 8];
#pragma unroll
        for (int dt = 0; dt < 4; ++dt) {
            short t[8];
#pragma unroll
            for (int j = 0; j < 8; ++j)
                t[j] = v_s[(16 * w + ks * 32 + qd * 8 + j) * 66 + 16 * dt + l16];
            bf16x8 bv = *(const bf16x8*)t;
            oacc[dt] = __builtin_amdgcn_mfma_f32_16x16x32_bf16(bv, ap, oacc[dt], 0, 0, 0);
        }
    }

    const size_t row = (size_t)(b * T + qs + 16 * w + l16);
#pragma unroll
    for (int dt = 0; dt < 4; ++dt) {
        short t[4];
#pragma unroll
        for (int r = 0; r < 4; ++r) t[r] = f2bf(oacc[dt][r]);
        *(uint2*)&attn_out[row * 1024 + h * 64 + dt * 16 + qd * 4] = *(const uint2*)t;
    }
}

extern "C" void kernel_launch(void* const* d_in, const int* in_sizes, int n_in,
                              void* d_out, int out_size, void* d_ws, size_t ws_size,
                              hipStream_t stream) {
    (void)in_sizes; (void)n_in; (void)out_size; (void)ws_size;
    const int B = 2, T = 2048, D = 1024;
    const int M = B * T;  // 4096

    char* ws = (char*)d_ws;
    size_t off = 0;
    short* xb   = (short*)(ws + off); off += (size_t)M * D * 2;       // 8.4 MB
    short* wqkb = (short*)(ws + off); off += (size_t)3 * D * D * 2;   // 6.3 MB
    short* wob  = (short*)(ws + off); off += (size_t)D * D * 2;       // 2.1 MB
    short* qkv  = (short*)(ws + off); off += (size_t)M * 3 * D * 2;   // 25.2 MB
    short* attn = (short*)(ws + off); off += (size_t)M * D * 2;       // 8.4 MB

    convert_all<<<dim3(4096), 256, 0, stream>>>(
        (const float*)d_in[0], (const float*)d_in[1], (const float*)d_in[3],
        xb, wqkb, wob);

    gemm1_qkv_8ph<<<dim3(192), 512, 0, stream>>>(
        xb, wqkb, (const float*)d_in[2], qkv, M, 3 * D, D);
    attn_mfma<<<dim3(T / 64, 16, B), 256, 0, stream>>>(qkv, attn, B, T);
    gemm2_out<<<dim3(D / 128, M / 64), 256, 0, stream>>>(
        attn, wob, (const float*)d_in[4], (float*)d_out, M, D, D);
}

// Round 11
// 154.306 us; speedup vs baseline: 1.0558x; 1.0558x over previous
//
#include <hip/hip_runtime.h>
#include <hip/hip_bf16.h>
#include <stdint.h>

// LocalSlidingWindowAttention: B=2, T=2048, D=1024, H=16, hd=64, keys j in [i, i+64].
// f32 in/out. Build:
//   convert_all (r7) -> gemm1_qkv_3cu (128x128 tile, BK=32, 4 waves,
//   3-deep counted-vmcnt pipeline, 48KB LDS -> 3 blocks/CU (768-block grid),
//   1 barrier/tile + XOR swizzle — r6 levers + m114 co-residency overlap)
//   -> attn_mfma (r3, proven) -> gemm2_out (r8, proven).
// gemm1 ladder (measured): 128^2 m97 drain0 43.7 (MfmaUtil 37%, 3/CU) ->
//   256^2 8ph drain0 46.0 (20%) -> 256^2 BK32 4-deep counted 42.3 (21%) ->
//   256^2 1-bar/tile+swz ~36 -> 256^2 m201-stagger 46.9 (20.5%, REGRESSED).
// Lesson: barrier count per MFMA dominates at 1 block/CU; co-residency is what
//   made 43.7's 37% MfmaUtil. This = fewest-barriers structure x 3 blocks/CU.
// NOTE r10: rounds 8-10 GPUAcquisitionTimeout; re-audited, resubmitted unchanged.

typedef short bf16x8 __attribute__((ext_vector_type(8)));
typedef float f32x4 __attribute__((ext_vector_type(4)));

typedef const __attribute__((address_space(1))) void* gptr_t;
typedef __attribute__((address_space(3))) void* lptr_t;

#define BAR()        asm volatile("s_barrier" ::: "memory")
#define WAIT_LGKM0() asm volatile("s_waitcnt lgkmcnt(0)" ::: "memory")

__device__ __forceinline__ float bf2f(short u) {
    union { float f; uint32_t i; } x;
    x.i = ((uint32_t)(uint16_t)u) << 16;
    return x.f;
}
__device__ __forceinline__ short f2bf(float f) {
    __hip_bfloat16 h = __float2bfloat16(f);  // RNE
    return *reinterpret_cast<short*>(&h);
}

// Convert x, w_qkv, w_out to bf16. 8 elems/thread.
__global__ __launch_bounds__(256)
void convert_all(const float* __restrict__ x, const float* __restrict__ wq,
                 const float* __restrict__ wo,
                 short* __restrict__ xb, short* __restrict__ wqb, short* __restrict__ wob) {
    int i = blockIdx.x * 256 + threadIdx.x;
    const float* src; short* dst; int o;
    if      (i <  524288) { src = x;  dst = xb;  o = i; }
    else if (i <  917504) { src = wq; dst = wqb; o = i - 524288; }
    else                  { src = wo; dst = wob; o = i - 917504; }
    const int e = o * 8;
    float4 a = *(const float4*)(src + e);
    float4 b = *(const float4*)(src + e + 4);
    short t[8];
    t[0] = f2bf(a.x); t[1] = f2bf(a.y); t[2] = f2bf(a.z); t[3] = f2bf(a.w);
    t[4] = f2bf(b.x); t[5] = f2bf(b.y); t[6] = f2bf(b.z); t[7] = f2bf(b.w);
    *(uint4*)(dst + e) = *(const uint4*)t;
}

// GEMM1: C[m,n] = sum_k A[m,k]*Bt[n,k] + bias[n], bf16 out. 128x128 tile, BK=32.
// 256 threads = 4 waves (2M x 2N), per-wave 64x64, acc[4][4].
// LDS: 3 bufs x (128x32 A + 128x32 B) = 48 KiB -> 3 blocks/CU; grid 768 = 3/CU.
// Per K-tile: {8 ds_read_b128 (swizzled); issue 4 gload_lds for tile kt+2;
//   lgkm0; 16 MFMA (setprio); vmcnt(4) [retires kt+1: outstanding kt+1(4)+kt+2(4)];
//   s_barrier}. One barrier per tile; co-resident blocks cover the stall.
// Tail: kt=nk-2 no issue, vmcnt(0); kt=nk-1 no issue/wait/barrier.
// Swizzle (both-sides, r6-verified): LDS[row][slot] holds global chunk
//   slot^((row>>1)&3); read slot qd^((l16>>1)&3) = per-thread const. Bank quad
//   4*(row&1)+slot -> 2 lanes/quad per quarter-wave = free (m136).
// Race: stage(kt+2) -> buf (kt+2)%3 == (kt-1)%3; its readers lgkm0'd + passed the
//   kt-1 end barrier before any wave enters kt and issues. Visibility: wave's own
//   loads for tile kt retired by its vmcnt at end of kt-1, published by the kt-1
//   barrier before any reader touches buf kt%3.
__global__ __launch_bounds__(256, 3)
void gemm1_qkv_3cu(const short* __restrict__ A, const short* __restrict__ Bt,
                   const float* __restrict__ bias, short* __restrict__ C,
                   int M, int N, int K) {
    __shared__ short As[3][128 * 32];   // 24 KiB
    __shared__ short Bs[3][128 * 32];   // 24 KiB

    const int tid  = threadIdx.x;
    const int lane = tid & 63;
    const int w    = tid >> 6;        // 0..3
    const int qd   = lane >> 4;       // 0..3
    const int l16  = lane & 15;
    const int wm   = w >> 1;          // 0..1 (64 rows each)
    const int wn   = w & 1;           // 0..1 (64 cols each)
    const int sx8  = (qd ^ ((l16 >> 1) & 3)) * 8;   // swizzled read slot (shorts)

    // XCD-chunked bijective swizzle (nwg=768, 768%8==0): chunk=96 = 4 m-panels x
    // 24 n-tiles per XCD -> A-panel L2 reuse within an XCD.
    const int nTn   = N >> 7;                     // 24
    const int chunk = gridDim.x >> 3;             // 96
    const int wg    = (blockIdx.x & 7) * chunk + (blockIdx.x >> 3);
    const int mt    = wg / nTn;
    const int nt    = wg - mt * nTn;
    const int mBase = mt << 7;
    const int nBase = nt << 7;

    // Staging: tile = 128 rows x 32 cols = 512 granules of 16B; 2 rounds of 256.
    // granule g = rr*256+tid: row=g>>2, stored slot=g&3, source chunk pre-XOR'd
    // (g&3)^((g>>3)&3) [= slot ^ ((row>>1)&3), the read involution].
    const short* gA[2];
    const short* gB[2];
#pragma unroll
    for (int rr = 0; rr < 2; ++rr) {
        const int g    = rr * 256 + tid;
        const int row  = g >> 2;
        const int slot = (g & 3) ^ ((g >> 3) & 3);
        gA[rr] = A  + (size_t)(mBase + row) * K + slot * 8;
        gB[rr] = Bt + (size_t)(nBase + row) * K + slot * 8;
    }

    f32x4 acc[4][4] = {};
    const int nk = K >> 5;                        // 32 (requires nk >= 3)

#define STAGE(T) { const int b_ = (T) % 3; const size_t ka_ = (size_t)(T) * 32;   \
    _Pragma("unroll")                                                             \
    for (int rr = 0; rr < 2; ++rr)                                                \
        __builtin_amdgcn_global_load_lds((gptr_t)(gA[rr] + ka_),                  \
            (lptr_t)(&As[b_][0] + (rr * 256 + w * 64) * 8), 16, 0, 0);            \
    _Pragma("unroll")                                                             \
    for (int rr = 0; rr < 2; ++rr)                                                \
        __builtin_amdgcn_global_load_lds((gptr_t)(gB[rr] + ka_),                  \
            (lptr_t)(&Bs[b_][0] + (rr * 256 + w * 64) * 8), 16, 0, 0); }

    // Prologue: stage tiles 0,1 (8 loads); retire tile 0 -> vmcnt(4).
    STAGE(0) STAGE(1)
    asm volatile("s_waitcnt vmcnt(4)" ::: "memory");
    BAR();

#define TILE_BODY(KT, DO_ISSUE, ENDWAIT, DO_BAR)                                  \
    {                                                                             \
        const int cur_ = (KT) % 3;                                                \
        const short* Ab_ = &As[cur_][0];                                          \
        const short* Bb_ = &Bs[cur_][0];                                          \
        bf16x8 af_[4], bfr_[4];                                                   \
        _Pragma("unroll")                                                         \
        for (int mi = 0; mi < 4; ++mi)                                            \
            af_[mi] = *(const bf16x8*)(Ab_ + (wm * 64 + mi * 16 + l16) * 32 + sx8); \
        _Pragma("unroll")                                                         \
        for (int ni = 0; ni < 4; ++ni)                                            \
            bfr_[ni] = *(const bf16x8*)(Bb_ + (wn * 64 + ni * 16 + l16) * 32 + sx8); \
        if (DO_ISSUE) STAGE((KT) + 2)                                             \
        WAIT_LGKM0();                                                             \
        __builtin_amdgcn_sched_barrier(0);                                        \
        __builtin_amdgcn_s_setprio(1);                                            \
        _Pragma("unroll")                                                         \
        for (int mi = 0; mi < 4; ++mi)                                            \
            _Pragma("unroll")                                                     \
            for (int ni = 0; ni < 4; ++ni)                                        \
                acc[mi][ni] = __builtin_amdgcn_mfma_f32_16x16x32_bf16(            \
                    af_[mi], bfr_[ni], acc[mi][ni], 0, 0, 0);                     \
        __builtin_amdgcn_s_setprio(0);                                            \
        ENDWAIT;                                                                  \
        if (DO_BAR) BAR();                                                        \
    }

    // Main: tiles 0..nk-3 issue kt+2, retire kt+1 via vmcnt(4).
    for (int kt = 0; kt < nk - 2; ++kt)
        TILE_BODY(kt, 1, asm volatile("s_waitcnt vmcnt(4)" ::: "memory"), 1)
    // Tail: nk-2 (4 outstanding -> vmcnt(0) retires nk-1), nk-1 (no wait/bar).
    TILE_BODY(nk - 2, 0, asm volatile("s_waitcnt vmcnt(0)" ::: "memory"), 1)
    TILE_BODY(nk - 1, 0, (void)0, 0)
#undef TILE_BODY
#undef STAGE

    // Epilogue: n = ..+l16 (lane-consecutive), m = ..+qd*4+rr (proven mapping).
#pragma unroll
    for (int nf = 0; nf < 4; ++nf) {
        const int n = nBase + wn * 64 + nf * 16 + l16;
        const float bv = bias[n];
#pragma unroll
        for (int mf = 0; mf < 4; ++mf)
#pragma unroll
            for (int rr = 0; rr < 4; ++rr) {
                const int m = mBase + wm * 64 + mf * 16 + qd * 4 + rr;
                C[(size_t)m * N + n] = f2bf(acc[mf][nf][rr] + bv);
            }
    }
}

// GEMM2 (r8 proven component): out = attn @ w_out^T + b_out, f32 out/bias.
// 64x128 tile, BK=32. Grid (8,64) = 512 blocks = 2/CU (12 KB LDS) -> drain overlap.
__global__ __launch_bounds__(256)
void gemm2_out(const short* __restrict__ A, const short* __restrict__ Bt,
               const float* __restrict__ bias, float* __restrict__ C,
               int M, int N, int K) {
    __shared__ short As[64 * 32];    // 4 KB
    __shared__ short Bs[128 * 32];   // 8 KB

    const int tid  = threadIdx.x;
    const int lane = tid & 63;
    const int w    = tid >> 6;
    const int qd   = lane >> 4;
    const int l16  = lane & 15;
    const int wm   = w >> 1;          // 32 rows each
    const int wn   = w & 1;           // 64 cols each
    const int mBase = blockIdx.y * 64;
    const int nBase = blockIdx.x * 128;

    f32x4 acc[2][4] = {};

    const int nK = K >> 5;
    for (int kt = 0; kt < nK; ++kt) {
        const int kb = kt << 5;
        {
            const int e   = tid * 8;            // A: 64x32, one chunk-round
            const int row = e >> 5;
            const int col = e & 31;
            const short* ga = A + (size_t)(mBase + row) * K + kb + col;
            lptr_t la = (lptr_t)(As + w * 512);
            __builtin_amdgcn_global_load_lds((gptr_t)ga, la, 16, 0, 0);
        }
#pragma unroll
        for (int i = 0; i < 2; ++i) {           // B: 128x32
            const int e   = i * 2048 + tid * 8;
            const int row = e >> 5;
            const int col = e & 31;
            const short* gb = Bt + (size_t)(nBase + row) * K + kb + col;
            lptr_t lb = (lptr_t)(Bs + i * 2048 + w * 512);
            __builtin_amdgcn_global_load_lds((gptr_t)gb, lb, 16, 0, 0);
        }
        __syncthreads();

        bf16x8 af[2], bfr[4];
#pragma unroll
        for (int mi = 0; mi < 2; ++mi)
            af[mi] = *(const bf16x8*)(As + (wm * 32 + mi * 16 + l16) * 32 + qd * 8);
#pragma unroll
        for (int ni = 0; ni < 4; ++ni)
            bfr[ni] = *(const bf16x8*)(Bs + (wn * 64 + ni * 16 + l16) * 32 + qd * 8);
#pragma unroll
        for (int mi = 0; mi < 2; ++mi)
#pragma unroll
            for (int ni = 0; ni < 4; ++ni)
                acc[mi][ni] = __builtin_amdgcn_mfma_f32_16x16x32_bf16(
                    af[mi], bfr[ni], acc[mi][ni], 0, 0, 0);
        __syncthreads();
    }

#pragma unroll
    for (int ni = 0; ni < 4; ++ni) {
        const int n = nBase + wn * 64 + ni * 16 + l16;
        const float bv = bias[n];
#pragma unroll
        for (int mi = 0; mi < 2; ++mi)
#pragma unroll
            for (int rr = 0; rr < 4; ++rr) {
                const int m = mBase + wm * 32 + mi * 16 + qd * 4 + rr;
                C[(size_t)m * N + n] = acc[mi][ni][rr] + bv;
            }
    }
}

// MFMA attention (r3, proven). Block = 64 queries x head x batch; 4 waves.
__global__ __launch_bounds__(256)
void attn_mfma(const short* __restrict__ qkv, short* __restrict__ attn_out, int B, int T) {
    __shared__ short k_s[128 * 72];
    __shared__ short v_s[144 * 66];
    __shared__ short p_s[64 * 104];

    const int tid  = threadIdx.x;
    const int lane = tid & 63;
    const int w    = tid >> 6;
    const int qd   = lane >> 4;
    const int l16  = lane & 15;
    const int qs   = blockIdx.x * 64;
    const int h    = blockIdx.y;
    const int b    = blockIdx.z;
    const size_t rs   = 3072;
    const size_t base = (size_t)b * T * rs;
    const int qoff = h * 64, koff = 1024 + h * 64, voff = 2048 + h * 64;

#pragma unroll
    for (int i = 0; i < 5; ++i) {
        const int c   = tid + i * 256;
        const int row = c >> 3;
        if (row >= 144) break;
        const int ch = (c & 7) * 8;
        int gr = qs + row; if (gr > T - 1) gr = T - 1;
        uint4 uv = *(const uint4*)(qkv + base + (size_t)gr * rs + voff + ch);
        if (row < 128) {
            uint4 uk = *(const uint4*)(qkv + base + (size_t)gr * rs + koff + ch);
            *(uint4*)&k_s[row * 72 + ch] = uk;
        }
        const uint32_t* vp = (const uint32_t*)&uv;
        uint32_t* vd = (uint32_t*)&v_s[row * 66 + ch];
        vd[0] = vp[0]; vd[1] = vp[1]; vd[2] = vp[2]; vd[3] = vp[3];
    }
    __syncthreads();

    bf16x8 aq0, aq1;
    {
        const short* g = qkv + base + (size_t)(qs + 16 * w + l16) * rs + qoff + qd * 8;
        aq0 = *(const bf16x8*)(g);
        aq1 = *(const bf16x8*)(g + 32);
    }

    f32x4 sacc[5] = {};
#pragma unroll
    for (int u = 0; u < 5; ++u) {
        const int krow = 16 * (w + u) + l16;
        bf16x8 bk0 = *(const bf16x8*)&k_s[krow * 72 + qd * 8];
        bf16x8 bk1 = *(const bf16x8*)&k_s[krow * 72 + 32 + qd * 8];
        sacc[u] = __builtin_amdgcn_mfma_f32_16x16x32_bf16(aq0, bk0, sacc[u], 0, 0, 0);
        sacc[u] = __builtin_amdgcn_mfma_f32_16x16x32_bf16(aq1, bk1, sacc[u], 0, 0, 0);
    }

    const float scale = 0.125f;
    float pw[5][4];
    float inv[4];
#pragma unroll
    for (int r = 0; r < 4; ++r) {
        const int m = 4 * qd + r;
        float mx = -3.4e38f;
#pragma unroll
        for (int u = 0; u < 5; ++u) {
            const int rel = 16 * u + l16 - m;
            const int j   = qs + 16 * (w + u) + l16;
            const bool ok = (rel >= 0) & (rel <= 64) & (j < T);
            const float v = ok ? sacc[u][r] * scale : -3.4e38f;
            pw[u][r] = v;
            mx = fmaxf(mx, v);
        }
#pragma unroll
        for (int msk = 1; msk <= 8; msk <<= 1) mx = fmaxf(mx, __shfl_xor(mx, msk));
        float sum = 0.f;
#pragma unroll
        for (int u = 0; u < 5; ++u) {
            float e = (pw[u][r] <= -3.0e38f) ? 0.f : __expf(pw[u][r] - mx);
            pw[u][r] = e;
            sum += e;
        }
#pragma unroll
        for (int msk = 1; msk <= 8; msk <<= 1) sum += __shfl_xor(sum, msk);
        inv[r] = 1.0f / sum;
    }

#pragma unroll
    for (int u = 0; u < 5; ++u)
#pragma unroll
        for (int r = 0; r < 4; ++r)
            p_s[(16 * w + 4 * qd + r) * 104 + 16 * u + l16] = f2bf(pw[u][r] * inv[r]);
#pragma unroll
    for (int r = 0; r < 4; ++r)
        p_s[(16 * w + 4 * qd + r) * 104 + 80 + l16] = 0;
    // wave-private rows; same-wave RAW -> lgkmcnt wait, no barrier needed

    f32x4 oacc[4] = {};
#pragma unroll
    for (int ks = 0; ks < 3; ++ks) {
        bf16x8 ap = *(const bf16x8*)&p_s[(16 * w + l16) * 104 + ks * 32 + qd * 8];
#pragma unroll
        for (int dt = 0; dt < 4; ++dt) {
            short t[8];
#pragma unroll
            for (int j = 0; j < 8; ++j)
                t[j] = v_s[(16 * w + ks * 32 + qd * 8 + j) * 66 + 16 * dt + l16];
            bf16x8 bv = *(const bf16x8*)t;
            oacc[dt] = __builtin_amdgcn_mfma_f32_16x16x32_bf16(bv, ap, oacc[dt], 0, 0, 0);
        }
    }

    const size_t row = (size_t)(b * T + qs + 16 * w + l16);
#pragma unroll
    for (int dt = 0; dt < 4; ++dt) {
        short t[4];
#pragma unroll
        for (int r = 0; r < 4; ++r) t[r] = f2bf(oacc[dt][r]);
        *(uint2*)&attn_out[row * 1024 + h * 64 + dt * 16 + qd * 4] = *(const uint2*)t;
    }
}

extern "C" void kernel_launch(void* const* d_in, const int* in_sizes, int n_in,
                              void* d_out, int out_size, void* d_ws, size_t ws_size,
                              hipStream_t stream) {
    (void)in_sizes; (void)n_in; (void)out_size; (void)ws_size;
    const int B = 2, T = 2048, D = 1024;
    const int M = B * T;  // 4096

    char* ws = (char*)d_ws;
    size_t off = 0;
    short* xb   = (short*)(ws + off); off += (size_t)M * D * 2;       // 8.4 MB
    short* wqkb = (short*)(ws + off); off += (size_t)3 * D * D * 2;   // 6.3 MB
    short* wob  = (short*)(ws + off); off += (size_t)D * D * 2;       // 2.1 MB
    short* qkv  = (short*)(ws + off); off += (size_t)M * 3 * D * 2;   // 25.2 MB
    short* attn = (short*)(ws + off); off += (size_t)M * D * 2;       // 8.4 MB

    convert_all<<<dim3(4096), 256, 0, stream>>>(
        (const float*)d_in[0], (const float*)d_in[1], (const float*)d_in[3],
        xb, wqkb, wob);

    gemm1_qkv_3cu<<<dim3(768), 256, 0, stream>>>(
        xb, wqkb, (const float*)d_in[2], qkv, M, 3 * D, D);
    attn_mfma<<<dim3(T / 64, 16, B), 256, 0, stream>>>(qkv, attn, B, T);
    gemm2_out<<<dim3(D / 128, M / 64), 256, 0, stream>>>(
        attn, wob, (const float*)d_in[4], (float*)d_out, M, D, D);
}

// Round 12
// 145.992 us; speedup vs baseline: 1.1160x; 1.0569x over previous
//
#include <hip/hip_runtime.h>
#include <hip/hip_bf16.h>
#include <stdint.h>

// LocalSlidingWindowAttention: B=2, T=2048, D=1024, H=16, hd=64, keys j in [i, i+64].
// f32 in/out. Build (r12):
//   convert_all (proven) -> gemm1_qkv_pipe (r6 EXACT: 256x256, BK=32, 4-deep
//   counted-vmcnt, 1 barrier/tile, XOR swizzle — best measured total 152.5us)
//   -> attn_mfma (r3, proven) -> gemm2_pipe (NEW: r8-validated structure ported
//   to gemm2 — 3-deep counted vmcnt(3), 1 bar/tile, both-sides XOR swizzle,
//   36KB LDS -> 2 blocks/CU at 512 blocks).
// gemm1 ladder (measured): m97 43.7 -> 8ph drain0 46.0 -> 4-deep counted 42.3 ->
//   r6 1-bar/tile+swz ~36 (total 152.5, BEST) -> m201-stagger 46.9 (REGRESSED) ->
//   128^2 3/CU ~38 (total 154.3, neutral). r12 keeps r6; upgrades gemm2 instead
//   (drain0+2 syncthreads/tile -> counted pipeline, pred 12->9us).

typedef short bf16x8 __attribute__((ext_vector_type(8)));
typedef float f32x4 __attribute__((ext_vector_type(4)));

typedef const __attribute__((address_space(1))) void* gptr_t;
typedef __attribute__((address_space(3))) void* lptr_t;

#define BAR()        asm volatile("s_barrier" ::: "memory")
#define WAIT_LGKM0() asm volatile("s_waitcnt lgkmcnt(0)" ::: "memory")

__device__ __forceinline__ float bf2f(short u) {
    union { float f; uint32_t i; } x;
    x.i = ((uint32_t)(uint16_t)u) << 16;
    return x.f;
}
__device__ __forceinline__ short f2bf(float f) {
    __hip_bfloat16 h = __float2bfloat16(f);  // RNE
    return *reinterpret_cast<short*>(&h);
}

// Convert x, w_qkv, w_out to bf16. 8 elems/thread.
__global__ __launch_bounds__(256)
void convert_all(const float* __restrict__ x, const float* __restrict__ wq,
                 const float* __restrict__ wo,
                 short* __restrict__ xb, short* __restrict__ wqb, short* __restrict__ wob) {
    int i = blockIdx.x * 256 + threadIdx.x;
    const float* src; short* dst; int o;
    if      (i <  524288) { src = x;  dst = xb;  o = i; }
    else if (i <  917504) { src = wq; dst = wqb; o = i - 524288; }
    else                  { src = wo; dst = wob; o = i - 917504; }
    const int e = o * 8;
    float4 a = *(const float4*)(src + e);
    float4 b = *(const float4*)(src + e + 4);
    short t[8];
    t[0] = f2bf(a.x); t[1] = f2bf(a.y); t[2] = f2bf(a.z); t[3] = f2bf(a.w);
    t[4] = f2bf(b.x); t[5] = f2bf(b.y); t[6] = f2bf(b.z); t[7] = f2bf(b.w);
    *(uint4*)(dst + e) = *(const uint4*)t;
}

// GEMM1 (r6 EXACT, measured-best): 256x256, BK=32, 4-deep counted-vmcnt pipeline,
// 1 barrier/tile. 512 threads = 8 waves (2M x 4N), per-wave 128x64, acc[8][4].
// LDS: 4 bufs x (256x32 A + 256x32 B) = 128 KiB.
// Per K-tile: {12 ds_read (af0,bfr | af1) split by sched_barrier; issue 4 gloads
// for tile kt+3; lgkmcnt(4); 16 MFMA; lgkmcnt(0); 16 MFMA; vmcnt(8); s_barrier}.
// vmcnt ledger: at ENDWAIT of kt, outstanding = kt+1,kt+2,kt+3 (12) -> vmcnt(8)
// retires exactly kt+1. Tail: vmcnt(4), vmcnt(0), none.
// Swizzle (both-sides): LDS[row][slot] holds chunk slot^((row>>1)&3); read slot
// qd^((l16>>1)&3) = per-thread const sx8.
__global__ __launch_bounds__(512, 1)
void gemm1_qkv_pipe(const short* __restrict__ A, const short* __restrict__ Bt,
                    const float* __restrict__ bias, short* __restrict__ C,
                    int M, int N, int K) {
    __shared__ short As[4][256 * 32];   // 64 KiB
    __shared__ short Bs[4][256 * 32];   // 64 KiB

    const int tid  = threadIdx.x;
    const int lane = tid & 63;
    const int w    = tid >> 6;        // 0..7
    const int qd   = lane >> 4;       // 0..3
    const int l16  = lane & 15;
    const int wm   = w >> 2;          // 0..1  (128 rows each)
    const int wn   = w & 3;           // 0..3  (64 cols each)
    const int sx8  = (qd ^ ((l16 >> 1) & 3)) * 8;   // swizzled read slot (shorts)

    // XCD-chunked bijective swizzle (nwg=192, 192%8==0).
    const int nTn   = N >> 8;                     // 12
    const int chunk = gridDim.x >> 3;             // 24
    const int wg    = (blockIdx.x & 7) * chunk + (blockIdx.x >> 3);
    const int mt    = wg / nTn;
    const int nt    = wg - mt * nTn;
    const int mBase = mt << 8;
    const int nBase = nt << 8;

    // Staging: tile = 256x32 = 1024 granules of 16B; granule g = rr*512+tid:
    // row=g>>2, stored slot=g&3, source chunk pre-XOR'd (g&3)^((g>>3)&3).
    const short* gA[2];
    const short* gB[2];
#pragma unroll
    for (int rr = 0; rr < 2; ++rr) {
        const int g    = rr * 512 + tid;
        const int row  = g >> 2;
        const int slot = (g & 3) ^ ((g >> 3) & 3);
        gA[rr] = A  + (size_t)(mBase + row) * K + slot * 8;
        gB[rr] = Bt + (size_t)(nBase + row) * K + slot * 8;
    }

    f32x4 acc[8][4] = {};
    const int nk = K >> 5;                        // 32

#define STAGE1(T) { const int b_ = (T) & 3; const size_t ka_ = (size_t)(T) * 32;  \
    _Pragma("unroll")                                                             \
    for (int rr = 0; rr < 2; ++rr)                                                \
        __builtin_amdgcn_global_load_lds((gptr_t)(gA[rr] + ka_),                  \
            (lptr_t)(&As[b_][0] + (rr * 512 + w * 64) * 8), 16, 0, 0);            \
    _Pragma("unroll")                                                             \
    for (int rr = 0; rr < 2; ++rr)                                                \
        __builtin_amdgcn_global_load_lds((gptr_t)(gB[rr] + ka_),                  \
            (lptr_t)(&Bs[b_][0] + (rr * 512 + w * 64) * 8), 16, 0, 0); }

    // Prologue: stage tiles 0,1,2 (12 loads); retire tile 0 -> vmcnt(8).
    STAGE1(0) STAGE1(1) STAGE1(2)
    asm volatile("s_waitcnt vmcnt(8)" ::: "memory");
    BAR();

#define TILE_BODY1(KT, DO_ISSUE, ENDWAIT)                                         \
    {                                                                             \
        const int cur_ = (KT) & 3;                                                \
        const short* Ab_ = &As[cur_][0];                                          \
        const short* Bb_ = &Bs[cur_][0];                                          \
        bf16x8 af0_[4], bfr_[4], af1_[4];                                         \
        _Pragma("unroll")                                                         \
        for (int mi = 0; mi < 4; ++mi)                                            \
            af0_[mi] = *(const bf16x8*)(Ab_ + (wm * 128 + mi * 16 + l16) * 32 + sx8); \
        _Pragma("unroll")                                                         \
        for (int ni = 0; ni < 4; ++ni)                                            \
            bfr_[ni] = *(const bf16x8*)(Bb_ + (wn * 64 + ni * 16 + l16) * 32 + sx8);  \
        __builtin_amdgcn_sched_barrier(0); /* pin: first 8 reads before af1 */    \
        _Pragma("unroll")                                                         \
        for (int mi = 0; mi < 4; ++mi)                                            \
            af1_[mi] = *(const bf16x8*)(Ab_ + (wm * 128 + 64 + mi * 16 + l16) * 32 + sx8); \
        if (DO_ISSUE) STAGE1((KT) + 3)                                            \
        asm volatile("s_waitcnt lgkmcnt(4)" ::: "memory"); /* af0+bfr landed */   \
        __builtin_amdgcn_sched_barrier(0);                                        \
        __builtin_amdgcn_s_setprio(1);                                            \
        _Pragma("unroll")                                                         \
        for (int mi = 0; mi < 4; ++mi)                                            \
            _Pragma("unroll")                                                     \
            for (int ni = 0; ni < 4; ++ni)                                        \
                acc[mi][ni] = __builtin_amdgcn_mfma_f32_16x16x32_bf16(            \
                    af0_[mi], bfr_[ni], acc[mi][ni], 0, 0, 0);                    \
        __builtin_amdgcn_s_setprio(0);                                            \
        WAIT_LGKM0();                                                             \
        __builtin_amdgcn_sched_barrier(0);                                        \
        __builtin_amdgcn_s_setprio(1);                                            \
        _Pragma("unroll")                                                         \
        for (int mi = 0; mi < 4; ++mi)                                            \
            _Pragma("unroll")                                                     \
            for (int ni = 0; ni < 4; ++ni)                                        \
                acc[mi + 4][ni] = __builtin_amdgcn_mfma_f32_16x16x32_bf16(        \
                    af1_[mi], bfr_[ni], acc[mi + 4][ni], 0, 0, 0);                \
        __builtin_amdgcn_s_setprio(0);                                            \
        ENDWAIT;                                                                  \
        BAR();                                                                    \
    }

    for (int kt = 0; kt < nk - 3; ++kt)
        TILE_BODY1(kt, 1, asm volatile("s_waitcnt vmcnt(8)" ::: "memory"))
    TILE_BODY1(nk - 3, 0, asm volatile("s_waitcnt vmcnt(4)" ::: "memory"))
    TILE_BODY1(nk - 2, 0, asm volatile("s_waitcnt vmcnt(0)" ::: "memory"))
    TILE_BODY1(nk - 1, 0, (void)0)
#undef TILE_BODY1
#undef STAGE1

    // Epilogue: n = ..+l16 (lane-consecutive), m = ..+qd*4+rr (proven mapping).
#pragma unroll
    for (int nf = 0; nf < 4; ++nf) {
        const int n = nBase + wn * 64 + nf * 16 + l16;
        const float bv = bias[n];
#pragma unroll
        for (int mf = 0; mf < 8; ++mf)
#pragma unroll
            for (int rr = 0; rr < 4; ++rr) {
                const int m = mBase + wm * 128 + mf * 16 + qd * 4 + rr;
                C[(size_t)m * N + n] = f2bf(acc[mf][nf][rr] + bv);
            }
    }
}

// GEMM2 (r12 NEW): out = attn @ w_out^T + b_out, f32 out/bias. 64x128 tile,
// BK=32, 3-deep counted-vmcnt pipeline (r8-validated structure), 1 bar/tile.
// 256 threads = 4 waves (2M x 2N), per-wave 32x64, acc[2][4].
// LDS: 3 bufs x (64x32 A + 128x32 B) = 36 KiB -> 2 blocks/CU at 512 blocks.
// Ledger (3 loads/tile: A(1)+B(2), strict order): prologue t0,t1 = 6 out ->
// vmcnt(3) retires t0; tile kt issues kt+2 (6 out) -> vmcnt(3) retires kt+1;
// tail vmcnt(0), none. Same both-sides XOR swizzle as gemm1 (kills the
// 4cyc/b128 conflict measured in r5 on this exact read pattern).
__global__ __launch_bounds__(256)
void gemm2_pipe(const short* __restrict__ A, const short* __restrict__ Bt,
                const float* __restrict__ bias, float* __restrict__ C,
                int M, int N, int K) {
    __shared__ short As[3][64 * 32];    // 12 KB
    __shared__ short Bs[3][128 * 32];   // 24 KB

    const int tid  = threadIdx.x;
    const int lane = tid & 63;
    const int w    = tid >> 6;
    const int qd   = lane >> 4;
    const int l16  = lane & 15;
    const int wm   = w >> 1;          // 32 rows each
    const int wn   = w & 1;           // 64 cols each
    const int sx8  = (qd ^ ((l16 >> 1) & 3)) * 8;
    const int mBase = blockIdx.y * 64;
    const int nBase = blockIdx.x * 128;

    // Staging sources (pre-XOR'd chunk): A = 64x32 = 256 granules (1 round);
    // B = 128x32 = 512 granules (2 rounds).
    const short* gA;
    {
        const int g = tid;
        gA = A + (size_t)(mBase + (g >> 2)) * K + (((g & 3) ^ ((g >> 3) & 3)) * 8);
    }
    const short* gB[2];
#pragma unroll
    for (int rr = 0; rr < 2; ++rr) {
        const int g = rr * 256 + tid;
        gB[rr] = Bt + (size_t)(nBase + (g >> 2)) * K + (((g & 3) ^ ((g >> 3) & 3)) * 8);
    }

    f32x4 acc[2][4] = {};
    const int nk = K >> 5;            // 32

#define STAGE2(T) { const int b_ = (T) % 3; const size_t ka_ = (size_t)(T) * 32;  \
    __builtin_amdgcn_global_load_lds((gptr_t)(gA + ka_),                          \
        (lptr_t)(&As[b_][0] + (w * 64) * 8), 16, 0, 0);                           \
    _Pragma("unroll")                                                             \
    for (int rr = 0; rr < 2; ++rr)                                                \
        __builtin_amdgcn_global_load_lds((gptr_t)(gB[rr] + ka_),                  \
            (lptr_t)(&Bs[b_][0] + (rr * 256 + w * 64) * 8), 16, 0, 0); }

    STAGE2(0) STAGE2(1)
    asm volatile("s_waitcnt vmcnt(3)" ::: "memory");   // retire tile 0
    BAR();

#define TILE_BODY2(KT, DO_ISSUE, ENDWAIT, DO_BAR)                                 \
    {                                                                             \
        const int cur_ = (KT) % 3;                                                \
        const short* Ab_ = &As[cur_][0];                                          \
        const short* Bb_ = &Bs[cur_][0];                                          \
        bf16x8 af_[2], bfr_[4];                                                   \
        _Pragma("unroll")                                                         \
        for (int mi = 0; mi < 2; ++mi)                                            \
            af_[mi] = *(const bf16x8*)(Ab_ + (wm * 32 + mi * 16 + l16) * 32 + sx8); \
        _Pragma("unroll")                                                         \
        for (int ni = 0; ni < 4; ++ni)                                            \
            bfr_[ni] = *(const bf16x8*)(Bb_ + (wn * 64 + ni * 16 + l16) * 32 + sx8); \
        if (DO_ISSUE) STAGE2((KT) + 2)                                            \
        WAIT_LGKM0();                                                             \
        __builtin_amdgcn_sched_barrier(0);                                        \
        __builtin_amdgcn_s_setprio(1);                                            \
        _Pragma("unroll")                                                         \
        for (int mi = 0; mi < 2; ++mi)                                            \
            _Pragma("unroll")                                                     \
            for (int ni = 0; ni < 4; ++ni)                                        \
                acc[mi][ni] = __builtin_amdgcn_mfma_f32_16x16x32_bf16(            \
                    af_[mi], bfr_[ni], acc[mi][ni], 0, 0, 0);                     \
        __builtin_amdgcn_s_setprio(0);                                            \
        ENDWAIT;                                                                  \
        if (DO_BAR) BAR();                                                        \
    }

    for (int kt = 0; kt < nk - 2; ++kt)
        TILE_BODY2(kt, 1, asm volatile("s_waitcnt vmcnt(3)" ::: "memory"), 1)
    TILE_BODY2(nk - 2, 0, asm volatile("s_waitcnt vmcnt(0)" ::: "memory"), 1)
    TILE_BODY2(nk - 1, 0, (void)0, 0)
#undef TILE_BODY2
#undef STAGE2

#pragma unroll
    for (int ni = 0; ni < 4; ++ni) {
        const int n = nBase + wn * 64 + ni * 16 + l16;
        const float bv = bias[n];
#pragma unroll
        for (int mi = 0; mi < 2; ++mi)
#pragma unroll
            for (int rr = 0; rr < 4; ++rr) {
                const int m = mBase + wm * 32 + mi * 16 + qd * 4 + rr;
                C[(size_t)m * N + n] = acc[mi][ni][rr] + bv;
            }
    }
}

// MFMA attention (r3, proven). Block = 64 queries x head x batch; 4 waves.
__global__ __launch_bounds__(256)
void attn_mfma(const short* __restrict__ qkv, short* __restrict__ attn_out, int B, int T) {
    __shared__ short k_s[128 * 72];
    __shared__ short v_s[144 * 66];
    __shared__ short p_s[64 * 104];

    const int tid  = threadIdx.x;
    const int lane = tid & 63;
    const int w    = tid >> 6;
    const int qd   = lane >> 4;
    const int l16  = lane & 15;
    const int qs   = blockIdx.x * 64;
    const int h    = blockIdx.y;
    const int b    = blockIdx.z;
    const size_t rs   = 3072;
    const size_t base = (size_t)b * T * rs;
    const int qoff = h * 64, koff = 1024 + h * 64, voff = 2048 + h * 64;

#pragma unroll
    for (int i = 0; i < 5; ++i) {
        const int c   = tid + i * 256;
        const int row = c >> 3;
        if (row >= 144) break;
        const int ch = (c & 7) * 8;
        int gr = qs + row; if (gr > T - 1) gr = T - 1;
        uint4 uv = *(const uint4*)(qkv + base + (size_t)gr * rs + voff + ch);
        if (row < 128) {
            uint4 uk = *(const uint4*)(qkv + base + (size_t)gr * rs + koff + ch);
            *(uint4*)&k_s[row * 72 + ch] = uk;
        }
        const uint32_t* vp = (const uint32_t*)&uv;
        uint32_t* vd = (uint32_t*)&v_s[row * 66 + ch];
        vd[0] = vp[0]; vd[1] = vp[1]; vd[2] = vp[2]; vd[3] = vp[3];
    }
    __syncthreads();

    bf16x8 aq0, aq1;
    {
        const short* g = qkv + base + (size_t)(qs + 16 * w + l16) * rs + qoff + qd * 8;
        aq0 = *(const bf16x8*)(g);
        aq1 = *(const bf16x8*)(g + 32);
    }

    f32x4 sacc[5] = {};
#pragma unroll
    for (int u = 0; u < 5; ++u) {
        const int krow = 16 * (w + u) + l16;
        bf16x8 bk0 = *(const bf16x8*)&k_s[krow * 72 + qd * 8];
        bf16x8 bk1 = *(const bf16x8*)&k_s[krow * 72 + 32 + qd * 8];
        sacc[u] = __builtin_amdgcn_mfma_f32_16x16x32_bf16(aq0, bk0, sacc[u], 0, 0, 0);
        sacc[u] = __builtin_amdgcn_mfma_f32_16x16x32_bf16(aq1, bk1, sacc[u], 0, 0, 0);
    }

    const float scale = 0.125f;
    float pw[5][4];
    float inv[4];
#pragma unroll
    for (int r = 0; r < 4; ++r) {
        const int m = 4 * qd + r;
        float mx = -3.4e38f;
#pragma unroll
        for (int u = 0; u < 5; ++u) {
            const int rel = 16 * u + l16 - m;
            const int j   = qs + 16 * (w + u) + l16;
            const bool ok = (rel >= 0) & (rel <= 64) & (j < T);
            const float v = ok ? sacc[u][r] * scale : -3.4e38f;
            pw[u][r] = v;
            mx = fmaxf(mx, v);
        }
#pragma unroll
        for (int msk = 1; msk <= 8; msk <<= 1) mx = fmaxf(mx, __shfl_xor(mx, msk));
        float sum = 0.f;
#pragma unroll
        for (int u = 0; u < 5; ++u) {
            float e = (pw[u][r] <= -3.0e38f) ? 0.f : __expf(pw[u][r] - mx);
            pw[u][r] = e;
            sum += e;
        }
#pragma unroll
        for (int msk = 1; msk <= 8; msk <<= 1) sum += __shfl_xor(sum, msk);
        inv[r] = 1.0f / sum;
    }

#pragma unroll
    for (int u = 0; u < 5; ++u)
#pragma unroll
        for (int r = 0; r < 4; ++r)
            p_s[(16 * w + 4 * qd + r) * 104 + 16 * u + l16] = f2bf(pw[u][r] * inv[r]);
#pragma unroll
    for (int r = 0; r < 4; ++r)
        p_s[(16 * w + 4 * qd + r) * 104 + 80 + l16] = 0;
    // wave-private rows; same-wave RAW -> lgkmcnt wait, no barrier needed

    f32x4 oacc[4] = {};
#pragma unroll
    for (int ks = 0; ks < 3; ++ks) {
        bf16x8 ap = *(const bf16x8*)&p_s[(16 * w + l16) * 104 + ks * 32 + qd * 8];
#pragma unroll
        for (int dt = 0; dt < 4; ++dt) {
            short t[8];
#pragma unroll
            for (int j = 0; j < 8; ++j)
                t[j] = v_s[(16 * w + ks * 32 + qd * 8 + j) * 66 + 16 * dt + l16];
            bf16x8 bv = *(const bf16x8*)t;
            oacc[dt] = __builtin_amdgcn_mfma_f32_16x16x32_bf16(bv, ap, oacc[dt], 0, 0, 0);
        }
    }

    const size_t row = (size_t)(b * T + qs + 16 * w + l16);
#pragma unroll
    for (int dt = 0; dt < 4; ++dt) {
        short t[4];
#pragma unroll
        for (int r = 0; r < 4; ++r) t[r] = f2bf(oacc[dt][r]);
        *(uint2*)&attn_out[row * 1024 + h * 64 + dt * 16 + qd * 4] = *(const uint2*)t;
    }
}

extern "C" void kernel_launch(void* const* d_in, const int* in_sizes, int n_in,
                              void* d_out, int out_size, void* d_ws, size_t ws_size,
                              hipStream_t stream) {
    (void)in_sizes; (void)n_in; (void)out_size; (void)ws_size;
    const int B = 2, T = 2048, D = 1024;
    const int M = B * T;  // 4096

    char* ws = (char*)d_ws;
    size_t off = 0;
    short* xb   = (short*)(ws + off); off += (size_t)M * D * 2;       // 8.4 MB
    short* wqkb = (short*)(ws + off); off += (size_t)3 * D * D * 2;   // 6.3 MB
    short* wob  = (short*)(ws + off); off += (size_t)D * D * 2;       // 2.1 MB
    short* qkv  = (short*)(ws + off); off += (size_t)M * 3 * D * 2;   // 25.2 MB
    short* attn = (short*)(ws + off); off += (size_t)M * D * 2;       // 8.4 MB

    convert_all<<<dim3(4096), 256, 0, stream>>>(
        (const float*)d_in[0], (const float*)d_in[1], (const float*)d_in[3],
        xb, wqkb, wob);

    gemm1_qkv_pipe<<<dim3(192), 512, 0, stream>>>(
        xb, wqkb, (const float*)d_in[2], qkv, M, 3 * D, D);
    attn_mfma<<<dim3(T / 64, 16, B), 256, 0, stream>>>(qkv, attn, B, T);
    gemm2_pipe<<<dim3(D / 128, M / 64), 256, 0, stream>>>(
        attn, wob, (const float*)d_in[4], (float*)d_out, M, D, D);
}